// Round 1
// 187.733 us; speedup vs baseline: 1.0446x; 1.0446x over previous
//
#include <hip/hip_runtime.h>
#include <hip/hip_bf16.h>
#include <math.h>

#define BB 4
#define CC 128
#define HH 128
#define WW 128
#define OO 256
#define HWP 16384   // H*W

typedef __attribute__((ext_vector_type(8))) _Float16 half8;   // f16x8 MFMA frag
typedef __attribute__((ext_vector_type(2))) _Float16 half2t;  // v_dot2 operand
typedef __attribute__((ext_vector_type(4))) float floatx4;    // MFMA C/D frag

__device__ inline half2t u2h2(unsigned int u) {
  union { unsigned int i; half2t h; } z; z.i = u; return z.h;
}
__device__ inline unsigned short f2h_bits(float f) {
  union { _Float16 h; unsigned short s; } z; z.h = (_Float16)f; return z.s;
}

// ---------------------------------------------------------------------------
// P1: fused NCHW->NHWC f16 transpose (z<4) + weight prep (z==4).
// ---------------------------------------------------------------------------
__global__ __launch_bounds__(256) void k_transpose(const float* __restrict__ x,
                                                   const float* __restrict__ w_off,
                                                   const float* __restrict__ w_pw,
                                                   unsigned int* __restrict__ xh32,
                                                   _Float16* __restrict__ Ah,
                                                   _Float16* __restrict__ Apw) {
  int tid = threadIdx.x;
  if (blockIdx.z == 4) {
    int e = (blockIdx.x * 128 + blockIdx.y) * 256 + tid;
    if (e < 144 * 32 * 8) {   // offconv A: [kblk=144][o=32][8], k = t*128+c
      int kblk = e >> 8;
      int o = (e >> 3) & 31;
      int j = e & 7;
      int k = kblk * 8 + j;
      int t = k >> 7, c = k & 127;
      float w = (o < 27) ? w_off[(o * CC + c) * 9 + t] : 0.0f;
      Ah[e] = (_Float16)w;
    }
    int e2 = e - 144 * 32 * 8;
    if (e2 >= 0 && e2 < 16 * 256 * 8) {   // pw A: [cblk=16][o=256][8]
      int cblk = e2 >> 11;
      int o = (e2 >> 3) & 255;
      int j = e2 & 7;
      Apw[e2] = (_Float16)w_pw[o * CC + cblk * 8 + j];
    }
    return;
  }
  __shared__ float tile[64][65];   // [c'][w']
  int wt = blockIdx.x & 1;
  int ct = blockIdx.x >> 1;
  int h = blockIdx.y, b = blockIdx.z;
  int tw = tid & 63;
  int tc = tid >> 6;
#pragma unroll
  for (int i = 0; i < 16; i++) {
    int c = ct * 64 + i * 4 + tc;
    tile[i * 4 + tc][tw] = x[((b * CC + c) * HH + h) * WW + wt * 64 + tw];
  }
  __syncthreads();
  int cp = tid & 31;        // channel pair within 64-ch tile
  int wq = tid >> 5;        // 8 w-groups
#pragma unroll
  for (int i = 0; i < 8; i++) {
    int wp = i * 8 + wq;    // w' in [0,64)
    int w = wt * 64 + wp;
    unsigned short h0 = f2h_bits(tile[cp * 2][wp]);
    unsigned short h1 = f2h_bits(tile[cp * 2 + 1][wp]);
    int idx2 = (((b * HH + h) * WW + w) * CC + ct * 64 + cp * 2) >> 1;
    xh32[idx2] = (unsigned int)h0 | ((unsigned int)h1 << 16);
  }
}

// ---------------------------------------------------------------------------
// P2: offset conv as f16 MFMA implicit GEMM (single precision term).
// Grid 512 XCD-swizzled; block = 4 waves = one image row; wave: 32 px x 32 o.
// Epilogue now writes om PIXEL-MAJOR [n][32] so k_sample's prologue reads one
// cache line per pixel instead of 27.
// ---------------------------------------------------------------------------
__global__ __launch_bounds__(256) void k_offconv_mfma(
    const _Float16* __restrict__ xh, const _Float16* __restrict__ Ah,
    const float* __restrict__ b_off, float* __restrict__ om) {
  int bid = blockIdx.x;
  int xcd = bid & 7, r = bid >> 3;
  int b = r >> 4;
  int h = xcd * 16 + (r & 15);
  int tid = threadIdx.x;
  int wv = tid >> 6, lane = tid & 63;
  int w0 = wv * 32;
  int n16 = lane & 15, quad = lane >> 4;

  floatx4 acc[2][2] = {};
  half8 zz = {};

  for (int t = 0; t < 9; t++) {
    int dy = t / 3 - 1, dx = t % 3 - 1;
    int hs = h + dy;
    bool hok = ((unsigned)hs < HH);
    int hsc = min(max(hs, 0), HH - 1);
    int wA = w0 + n16 + dx;
    int wB = wA + 16;
    bool okA = hok && ((unsigned)wA < WW);
    bool okB = hok && ((unsigned)wB < WW);
    int wAc = min(max(wA, 0), WW - 1);
    int wBc = min(max(wB, 0), WW - 1);
    size_t offA = (size_t)((b * HH + hsc) * WW + wAc) * CC + quad * 8;
    size_t offB = (size_t)((b * HH + hsc) * WW + wBc) * CC + quad * 8;
#pragma unroll
    for (int cs = 0; cs < 4; cs++) {
      int co = cs * 32;
      half8 bhA = *(const half8*)(xh + offA + co);
      half8 bhB = *(const half8*)(xh + offB + co);
      bhA = okA ? bhA : zz;
      bhB = okB ? bhB : zz;
      int kblk = t * 16 + cs * 4 + quad;
      const _Float16* pa = Ah + (size_t)kblk * 256 + n16 * 8;
      half8 a0 = *(const half8*)pa;
      half8 a1 = *(const half8*)(pa + 128);
      acc[0][0] = __builtin_amdgcn_mfma_f32_16x16x32_f16(a0, bhA, acc[0][0], 0, 0, 0);
      acc[1][0] = __builtin_amdgcn_mfma_f32_16x16x32_f16(a1, bhA, acc[1][0], 0, 0, 0);
      acc[0][1] = __builtin_amdgcn_mfma_f32_16x16x32_f16(a0, bhB, acc[0][1], 0, 0, 0);
      acc[1][1] = __builtin_amdgcn_mfma_f32_16x16x32_f16(a1, bhB, acc[1][1], 0, 0, 0);
    }
  }
  int nbase = (b << 14) + (h << 7);
#pragma unroll
  for (int mt = 0; mt < 2; mt++) {
#pragma unroll
    for (int reg = 0; reg < 4; reg++) {
      int o = mt * 16 + quad * 4 + reg;
      if (o < 27) {
        float bo = b_off[o];
#pragma unroll
        for (int nf = 0; nf < 2; nf++) {
          int w = w0 + nf * 16 + n16;
          om[((size_t)(nbase + w) << 5) + o] = acc[mt][nf][reg] + bo;
        }
      }
    }
  }
}

// ---------------------------------------------------------------------------
// P3: deformable sampling + mask + depthwise, f16 gather + v_dot2_f32_f16.
// Changes vs prev: (1) depthwise weights live in LDS s_wk[9][128] (one
// ds_read_b128 per tap) instead of a 36-VGPR per-thread array that starved
// the register allocator (VGPR_Count was 48 -> gather loads serialized);
// (2) om is pixel-major -> prologue reads 1 cache line per pixel, not 27;
// (3) __launch_bounds__(256,4) lets the compiler use up to 128 VGPRs to
// keep many gather loads in flight.
// ---------------------------------------------------------------------------
__global__ __launch_bounds__(256, 4) void k_sample(const unsigned short* __restrict__ xh,
                                                   const float* __restrict__ om,
                                                   const float* __restrict__ w_dw,
                                                   const float* __restrict__ b_dw,
                                                   unsigned short* __restrict__ out1h) {
  __shared__ int s_base[8][9], s_dxs[8][9], s_dys[8][9];
  __shared__ unsigned int s_wp[8][9][2];   // packed half2 (w00,w01),(w10,w11)
  __shared__ float s_wk[9][128];           // depthwise weights [tap][channel]
  int tid = threadIdx.x;
  int bid = blockIdx.x;
  int n0 = ((bid & 7) * 1024 + (bid >> 3)) * 8;   // XCD-contiguous bands

  // stage depthwise weights: w_dw[c*9+k] -> s_wk[k][c]
  for (int i = tid; i < 1152; i += 256) s_wk[i % 9][i / 9] = w_dw[i];

  if (tid < 72) {
    int pix = tid / 9, k = tid - pix * 9;
    int n = n0 + pix;
    int b = n >> 14, rem = n & 16383;
    int h = rem >> 7, w = rem & 127;
    const float* op = om + ((size_t)n << 5);   // pixel-major: one 128B line
    float dy = op[2 * k];
    float dx = op[2 * k + 1];
    float mv = op[18 + k];
    mv = 1.0f / (1.0f + __expf(-mv));
    float py = (float)(h + k / 3 - 1) + dy;
    float px = (float)(w + k % 3 - 1) + dx;
    float y0f = floorf(py), x0f = floorf(px);
    float wy = py - y0f, wx = px - x0f;
    int y0 = (int)y0f, x0 = (int)x0f;
    int y1 = y0 + 1, x1 = x0 + 1;
    float v00 = (y0 >= 0 && y0 < HH && x0 >= 0 && x0 < WW) ? 1.f : 0.f;
    float v01 = (y0 >= 0 && y0 < HH && x1 >= 0 && x1 < WW) ? 1.f : 0.f;
    float v10 = (y1 >= 0 && y1 < HH && x0 >= 0 && x0 < WW) ? 1.f : 0.f;
    float v11 = (y1 >= 0 && y1 < HH && x1 >= 0 && x1 < WW) ? 1.f : 0.f;
    int y0c = min(max(y0, 0), HH - 1), y1c = min(max(y1, 0), HH - 1);
    int x0c = min(max(x0, 0), WW - 1), x1c = min(max(x1, 0), WW - 1);
    s_base[pix][k] = ((b * HH + y0c) * WW + x0c) * CC;
    s_dxs[pix][k] = (x1c - x0c) * CC;
    s_dys[pix][k] = (y1c - y0c) * WW * CC;
    float w00 = (1.f - wy) * (1.f - wx) * mv * v00;
    float w01 = (1.f - wy) * wx * mv * v01;
    float w10 = wy * (1.f - wx) * mv * v10;
    float w11 = wy * wx * mv * v11;
    s_wp[pix][k][0] = (unsigned int)f2h_bits(w00) | ((unsigned int)f2h_bits(w01) << 16);
    s_wp[pix][k][1] = (unsigned int)f2h_bits(w10) | ((unsigned int)f2h_bits(w11) << 16);
  }
  __syncthreads();
  int wv = tid >> 6, lane = tid & 63;
  int pix = wv * 2 + (lane >> 5);
  int cl = lane & 31;
  int c0 = cl * 4;
  int n = n0 + pix;

  float acc0 = 0.f, acc1 = 0.f, acc2v = 0.f, acc3 = 0.f;
#pragma unroll
  for (int k = 0; k < 9; k++) {
    int base = s_base[pix][k] + c0;
    int dxs = s_dxs[pix][k], dys = s_dys[pix][k];
    uint2 a00 = *(const uint2*)(xh + base);
    uint2 a01 = *(const uint2*)(xh + base + dxs);
    uint2 a10 = *(const uint2*)(xh + base + dys);
    uint2 a11 = *(const uint2*)(xh + base + dys + dxs);
    half2t wt = u2h2(s_wp[pix][k][0]);
    half2t wb = u2h2(s_wp[pix][k][1]);
    // pack per-channel corner pairs: (top0|top1) and (bot0|bot1)
    unsigned int t0 = __builtin_amdgcn_perm(a01.x, a00.x, 0x05040100u);
    unsigned int t1 = __builtin_amdgcn_perm(a01.x, a00.x, 0x07060302u);
    unsigned int t2 = __builtin_amdgcn_perm(a01.y, a00.y, 0x05040100u);
    unsigned int t3 = __builtin_amdgcn_perm(a01.y, a00.y, 0x07060302u);
    unsigned int b0 = __builtin_amdgcn_perm(a11.x, a10.x, 0x05040100u);
    unsigned int b1 = __builtin_amdgcn_perm(a11.x, a10.x, 0x07060302u);
    unsigned int b2 = __builtin_amdgcn_perm(a11.y, a10.y, 0x05040100u);
    unsigned int b3 = __builtin_amdgcn_perm(a11.y, a10.y, 0x07060302u);
    float v0 = __builtin_amdgcn_fdot2(u2h2(b0), wb, __builtin_amdgcn_fdot2(u2h2(t0), wt, 0.f, false), false);
    float v1 = __builtin_amdgcn_fdot2(u2h2(b1), wb, __builtin_amdgcn_fdot2(u2h2(t1), wt, 0.f, false), false);
    float v2 = __builtin_amdgcn_fdot2(u2h2(b2), wb, __builtin_amdgcn_fdot2(u2h2(t2), wt, 0.f, false), false);
    float v3 = __builtin_amdgcn_fdot2(u2h2(b3), wb, __builtin_amdgcn_fdot2(u2h2(t3), wt, 0.f, false), false);
    float4 wv4 = *(const float4*)&s_wk[k][c0];
    acc0 = fmaf(v0, wv4.x, acc0);
    acc1 = fmaf(v1, wv4.y, acc1);
    acc2v = fmaf(v2, wv4.z, acc2v);
    acc3 = fmaf(v3, wv4.w, acc3);
  }
  float4 bd = *(const float4*)(b_dw + c0);
  acc0 += bd.x; acc1 += bd.y; acc2v += bd.z; acc3 += bd.w;
  ushort4 ov;
  ov.x = f2h_bits(acc0);
  ov.y = f2h_bits(acc1);
  ov.z = f2h_bits(acc2v);
  ov.w = f2h_bits(acc3);
  *(ushort4*)(out1h + (size_t)n * CC + c0) = ov;
}

// ---------------------------------------------------------------------------
// P4: pointwise GEMM, f16 MFMA. Block = 4 waves; block tile 256o x 64n.
// ---------------------------------------------------------------------------
__global__ __launch_bounds__(256) void k_pw_mfma(const _Float16* __restrict__ Apw,
                                                 const _Float16* __restrict__ out1h,
                                                 const float* __restrict__ bpw,
                                                 float* __restrict__ out) {
  int bid = blockIdx.x;
  int n0 = ((bid & 7) * 128 + (bid >> 3)) * 64;
  int tid = threadIdx.x;
  int wv = tid >> 6, lane = tid & 63;
  int n16 = lane & 15, quad = lane >> 4;
  int obase = wv * 64;

  floatx4 acc[4][4] = {};   // [mf][nf]
#pragma unroll
  for (int cs = 0; cs < 4; cs++) {
    half8 af[4], bf[4];
#pragma unroll
    for (int mf = 0; mf < 4; mf++) {
      const _Float16* pa = Apw + ((size_t)(cs * 4 + quad) * 256 + obase + mf * 16 + n16) * 8;
      af[mf] = *(const half8*)pa;
    }
#pragma unroll
    for (int nf = 0; nf < 4; nf++) {
      const _Float16* pb = out1h + (size_t)(n0 + nf * 16 + n16) * CC + cs * 32 + quad * 8;
      bf[nf] = *(const half8*)pb;
    }
#pragma unroll
    for (int mf = 0; mf < 4; mf++)
#pragma unroll
      for (int nf = 0; nf < 4; nf++)
        acc[mf][nf] = __builtin_amdgcn_mfma_f32_16x16x32_f16(af[mf], bf[nf], acc[mf][nf], 0, 0, 0);
  }
  int b = n0 >> 14;
#pragma unroll
  for (int mf = 0; mf < 4; mf++) {
#pragma unroll
    for (int reg = 0; reg < 4; reg++) {
      int o = obase + mf * 16 + quad * 4 + reg;
      float bo = bpw[o];
#pragma unroll
      for (int nf = 0; nf < 4; nf++) {
        int n = n0 + nf * 16 + n16;
        int hw = n & 16383;
        out[((size_t)(b * OO + o) << 14) + hw] = acc[mf][nf][reg] + bo;
      }
    }
  }
}

// ---------------------------------------------------------------------------
extern "C" void kernel_launch(void* const* d_in, const int* in_sizes, int n_in,
                              void* d_out, int out_size, void* d_ws, size_t ws_size,
                              hipStream_t stream) {
  const float* x     = (const float*)d_in[0];
  const float* w_off = (const float*)d_in[1];
  const float* b_off = (const float*)d_in[2];
  const float* w_dw  = (const float*)d_in[3];
  const float* b_dw  = (const float*)d_in[4];
  const float* w_pw  = (const float*)d_in[5];
  const float* b_pw  = (const float*)d_in[6];
  float* out = (float*)d_out;
  float* ws  = (float*)d_ws;

  // d_out scratch (dead before k_pw_mfma writes):
  //   xh  : f16 NHWC, 8388608 elems = 16.78 MB at byte offset 0
  //   om  : f32 pixel-major [65536][32] = 8.39 MB at float offset 4194304
  // (out region is 67 MB; both are fully overwritten by k_pw_mfma's output)
  _Float16* xh = (_Float16*)out;
  float* om = out + 4194304;

  // ws layout (float offsets):
  //   out1h : f16, 8388608 elems = 4194304 floats -> [0, 4194304)
  //   Ah    : f16 36864  -> at 4194304
  //   Apw   : f16 32768
  _Float16* out1h = (_Float16*)ws;
  _Float16* Ah = (_Float16*)(ws + 4194304);
  _Float16* Apw = Ah + 36864;

  k_transpose<<<dim3(4, 128, 5), 256, 0, stream>>>(x, w_off, w_pw,
                                                   (unsigned int*)xh, Ah, Apw);
  k_offconv_mfma<<<512, 256, 0, stream>>>(xh, Ah, b_off, om);
  k_sample<<<8192, 256, 0, stream>>>((const unsigned short*)xh, om, w_dw, b_dw,
                                     (unsigned short*)out1h);
  k_pw_mfma<<<1024, 256, 0, stream>>>(Apw, out1h, b_pw, out);
}

// Round 2
// 179.286 us; speedup vs baseline: 1.0938x; 1.0471x over previous
//
#include <hip/hip_runtime.h>
#include <hip/hip_bf16.h>
#include <math.h>

#define BB 4
#define CC 128
#define HH 128
#define WW 128
#define OO 256
#define HWP 16384   // H*W

typedef __attribute__((ext_vector_type(8))) _Float16 half8;   // f16x8 MFMA frag
typedef __attribute__((ext_vector_type(2))) _Float16 half2t;  // v_dot2 operand
typedef __attribute__((ext_vector_type(4))) float floatx4;    // MFMA C/D frag

__device__ inline half2t u2h2(unsigned int u) {
  union { unsigned int i; half2t h; } z; z.i = u; return z.h;
}
__device__ inline unsigned short f2h_bits(float f) {
  union { _Float16 h; unsigned short s; } z; z.h = (_Float16)f; return z.s;
}

// ---------------------------------------------------------------------------
// P1: fused NCHW->NHWC f16 transpose (z<4) + weight prep (z==4).
// ---------------------------------------------------------------------------
__global__ __launch_bounds__(256) void k_transpose(const float* __restrict__ x,
                                                   const float* __restrict__ w_off,
                                                   const float* __restrict__ w_pw,
                                                   unsigned int* __restrict__ xh32,
                                                   _Float16* __restrict__ Ah,
                                                   _Float16* __restrict__ Apw) {
  int tid = threadIdx.x;
  if (blockIdx.z == 4) {
    int e = (blockIdx.x * 128 + blockIdx.y) * 256 + tid;
    if (e < 144 * 32 * 8) {   // offconv A: [kblk=144][o=32][8], k = t*128+c
      int kblk = e >> 8;
      int o = (e >> 3) & 31;
      int j = e & 7;
      int k = kblk * 8 + j;
      int t = k >> 7, c = k & 127;
      float w = (o < 27) ? w_off[(o * CC + c) * 9 + t] : 0.0f;
      Ah[e] = (_Float16)w;
    }
    int e2 = e - 144 * 32 * 8;
    if (e2 >= 0 && e2 < 16 * 256 * 8) {   // pw A: [cblk=16][o=256][8]
      int cblk = e2 >> 11;
      int o = (e2 >> 3) & 255;
      int j = e2 & 7;
      Apw[e2] = (_Float16)w_pw[o * CC + cblk * 8 + j];
    }
    return;
  }
  __shared__ float tile[64][65];   // [c'][w']
  int wt = blockIdx.x & 1;
  int ct = blockIdx.x >> 1;
  int h = blockIdx.y, b = blockIdx.z;
  int tw = tid & 63;
  int tc = tid >> 6;
#pragma unroll
  for (int i = 0; i < 16; i++) {
    int c = ct * 64 + i * 4 + tc;
    tile[i * 4 + tc][tw] = x[((b * CC + c) * HH + h) * WW + wt * 64 + tw];
  }
  __syncthreads();
  int cp = tid & 31;        // channel pair within 64-ch tile
  int wq = tid >> 5;        // 8 w-groups
#pragma unroll
  for (int i = 0; i < 8; i++) {
    int wp = i * 8 + wq;    // w' in [0,64)
    int w = wt * 64 + wp;
    unsigned short h0 = f2h_bits(tile[cp * 2][wp]);
    unsigned short h1 = f2h_bits(tile[cp * 2 + 1][wp]);
    int idx2 = (((b * HH + h) * WW + w) * CC + ct * 64 + cp * 2) >> 1;
    xh32[idx2] = (unsigned int)h0 | ((unsigned int)h1 << 16);
  }
}

// ---------------------------------------------------------------------------
// P2+P3 FUSED: offset-conv (MFMA, K-split over 4 waves) + reduce(+bias) in
// LDS + deformable sampling with 4 pixels/thread.
//   Block = 32 consecutive pixels of one row. Grid 2048, XCD-swizzled.
//   Phase A: wave wv computes 32px x 32o partial over (t,cs) chunks
//            ki = wv*9 .. wv*9+8 (of 36). Partials -> LDS (stride-34 pad).
//   Reduce: 256 thr x 4 items sum 4 wave-partials, +b_off -> om_s[px][o].
//   Prologue: 288 items (px,k) -> bilinear bases/weights in LDS (overlays
//            the dead partial buffer via union).
//   Phase B: thread owns 4 channels x 4 pixels -> 16 gathers in flight/tap.
// ---------------------------------------------------------------------------
__global__ __launch_bounds__(256, 4) void k_fused(
    const _Float16* __restrict__ xh, const _Float16* __restrict__ Ah,
    const float* __restrict__ b_off, const float* __restrict__ w_dw,
    const float* __restrict__ b_dw, unsigned short* __restrict__ out1h) {
  __shared__ union SM {
    float part[4][32][34];          // [wave][o][px] padded: 2-way max conflicts
    struct {
      int s_base[32][9];
      int s_dxs[32][9];
      int s_dys[32][9];
      unsigned int s_wp[32][9][2];  // packed half2 (w00,w01),(w10,w11)
      float s_wk[9][128];           // depthwise weights [tap][channel]
    } p2;
  } sm;
  __shared__ float om_s[32][28];    // [px][o<27]

  int tid = threadIdx.x;
  int bid = blockIdx.x;
  int n0 = ((bid & 7) * 256 + (bid >> 3)) * 32;   // XCD-contiguous bands
  int b = n0 >> 14;
  int h0 = (n0 >> 7) & 127;
  int wbase = n0 & 127;

  int wv = tid >> 6, lane = tid & 63;
  int n16 = lane & 15, quad = lane >> 4;

  // ---- Phase A: offset conv, K-split: wave wv handles ki = wv*9 .. wv*9+8
  {
    floatx4 acc[2][2] = {};
    half8 zz = {};
#pragma unroll
    for (int kidx = 0; kidx < 9; kidx++) {
      int ki = wv * 9 + kidx;
      int t = ki >> 2, cs = ki & 3;
      int dy = t / 3 - 1, dx = t % 3 - 1;
      int hs = h0 + dy;
      bool hok = ((unsigned)hs < HH);
      int hsc = min(max(hs, 0), HH - 1);
      int wA = wbase + n16 + dx;
      int wB = wA + 16;
      bool okA = hok && ((unsigned)wA < WW);
      bool okB = hok && ((unsigned)wB < WW);
      int wAc = min(max(wA, 0), WW - 1);
      int wBc = min(max(wB, 0), WW - 1);
      size_t offA = (size_t)((b * HH + hsc) * WW + wAc) * CC + cs * 32 + quad * 8;
      size_t offB = (size_t)((b * HH + hsc) * WW + wBc) * CC + cs * 32 + quad * 8;
      half8 bhA = *(const half8*)(xh + offA);
      half8 bhB = *(const half8*)(xh + offB);
      bhA = okA ? bhA : zz;
      bhB = okB ? bhB : zz;
      int kblk = t * 16 + cs * 4 + quad;
      const _Float16* pa = Ah + (size_t)kblk * 256 + n16 * 8;
      half8 a0 = *(const half8*)pa;
      half8 a1 = *(const half8*)(pa + 128);
      acc[0][0] = __builtin_amdgcn_mfma_f32_16x16x32_f16(a0, bhA, acc[0][0], 0, 0, 0);
      acc[1][0] = __builtin_amdgcn_mfma_f32_16x16x32_f16(a1, bhA, acc[1][0], 0, 0, 0);
      acc[0][1] = __builtin_amdgcn_mfma_f32_16x16x32_f16(a0, bhB, acc[0][1], 0, 0, 0);
      acc[1][1] = __builtin_amdgcn_mfma_f32_16x16x32_f16(a1, bhB, acc[1][1], 0, 0, 0);
    }
#pragma unroll
    for (int mt = 0; mt < 2; mt++)
#pragma unroll
      for (int reg = 0; reg < 4; reg++)
#pragma unroll
        for (int nf = 0; nf < 2; nf++)
          sm.part[wv][mt * 16 + quad * 4 + reg][nf * 16 + n16] = acc[mt][nf][reg];
  }
  __syncthreads();

  // ---- Reduce 4 wave-partials, add bias -> om_s[px][o]
#pragma unroll
  for (int i = 0; i < 4; i++) {
    int idx = tid + i * 256;
    int o = idx >> 5, px = idx & 31;
    float v = sm.part[0][o][px] + sm.part[1][o][px] + sm.part[2][o][px] + sm.part[3][o][px];
    if (o < 27) om_s[px][o] = v + b_off[o];
  }
  __syncthreads();   // part buffer now dead; p2 overlays it

  // ---- Prologue: depthwise weights + per-(px,tap) bilinear setup
  for (int i = tid; i < 1152; i += 256) sm.p2.s_wk[i % 9][i / 9] = w_dw[i];
  for (int it = tid; it < 288; it += 256) {
    int px = it / 9, k = it - px * 9;
    int w = wbase + px;
    float dyv = om_s[px][2 * k];
    float dxv = om_s[px][2 * k + 1];
    float mv = om_s[px][18 + k];
    mv = 1.0f / (1.0f + __expf(-mv));
    float py = (float)(h0 + k / 3 - 1) + dyv;
    float pxf = (float)(w + k % 3 - 1) + dxv;
    float y0f = floorf(py), x0f = floorf(pxf);
    float wy = py - y0f, wx = pxf - x0f;
    int y0 = (int)y0f, x0 = (int)x0f;
    int y1 = y0 + 1, x1 = x0 + 1;
    float v00 = (y0 >= 0 && y0 < HH && x0 >= 0 && x0 < WW) ? 1.f : 0.f;
    float v01 = (y0 >= 0 && y0 < HH && x1 >= 0 && x1 < WW) ? 1.f : 0.f;
    float v10 = (y1 >= 0 && y1 < HH && x0 >= 0 && x0 < WW) ? 1.f : 0.f;
    float v11 = (y1 >= 0 && y1 < HH && x1 >= 0 && x1 < WW) ? 1.f : 0.f;
    int y0c = min(max(y0, 0), HH - 1), y1c = min(max(y1, 0), HH - 1);
    int x0c = min(max(x0, 0), WW - 1), x1c = min(max(x1, 0), WW - 1);
    sm.p2.s_base[px][k] = ((b * HH + y0c) * WW + x0c) * CC;
    sm.p2.s_dxs[px][k] = (x1c - x0c) * CC;
    sm.p2.s_dys[px][k] = (y1c - y0c) * WW * CC;
    float w00 = (1.f - wy) * (1.f - wx) * mv * v00;
    float w01 = (1.f - wy) * wx * mv * v01;
    float w10 = wy * (1.f - wx) * mv * v10;
    float w11 = wy * wx * mv * v11;
    sm.p2.s_wp[px][k][0] = (unsigned int)f2h_bits(w00) | ((unsigned int)f2h_bits(w01) << 16);
    sm.p2.s_wp[px][k][1] = (unsigned int)f2h_bits(w10) | ((unsigned int)f2h_bits(w11) << 16);
  }
  __syncthreads();

  // ---- Phase B: sampling + depthwise, 4 pixels per thread
  int pg = wv * 2 + (lane >> 5);     // pixel group base [0,8)
  int cl = lane & 31;
  int c0 = cl * 4;
  const unsigned short* xs = (const unsigned short*)xh;

  float ac[4][4];
#pragma unroll
  for (int p = 0; p < 4; p++)
#pragma unroll
    for (int j = 0; j < 4; j++) ac[p][j] = 0.f;

#pragma unroll
  for (int k = 0; k < 9; k++) {
    float4 wk4 = *(const float4*)&sm.p2.s_wk[k][c0];
#pragma unroll
    for (int p = 0; p < 4; p++) {
      int pix = pg + p * 8;
      int base = sm.p2.s_base[pix][k] + c0;
      int dxs = sm.p2.s_dxs[pix][k], dys = sm.p2.s_dys[pix][k];
      uint2 a00 = *(const uint2*)(xs + base);
      uint2 a01 = *(const uint2*)(xs + base + dxs);
      uint2 a10 = *(const uint2*)(xs + base + dys);
      uint2 a11 = *(const uint2*)(xs + base + dys + dxs);
      half2t wt = u2h2(sm.p2.s_wp[pix][k][0]);
      half2t wb = u2h2(sm.p2.s_wp[pix][k][1]);
      unsigned int t0 = __builtin_amdgcn_perm(a01.x, a00.x, 0x05040100u);
      unsigned int t1 = __builtin_amdgcn_perm(a01.x, a00.x, 0x07060302u);
      unsigned int t2 = __builtin_amdgcn_perm(a01.y, a00.y, 0x05040100u);
      unsigned int t3 = __builtin_amdgcn_perm(a01.y, a00.y, 0x07060302u);
      unsigned int b0 = __builtin_amdgcn_perm(a11.x, a10.x, 0x05040100u);
      unsigned int b1 = __builtin_amdgcn_perm(a11.x, a10.x, 0x07060302u);
      unsigned int b2 = __builtin_amdgcn_perm(a11.y, a10.y, 0x05040100u);
      unsigned int b3 = __builtin_amdgcn_perm(a11.y, a10.y, 0x07060302u);
      float v0 = __builtin_amdgcn_fdot2(u2h2(b0), wb, __builtin_amdgcn_fdot2(u2h2(t0), wt, 0.f, false), false);
      float v1 = __builtin_amdgcn_fdot2(u2h2(b1), wb, __builtin_amdgcn_fdot2(u2h2(t1), wt, 0.f, false), false);
      float v2 = __builtin_amdgcn_fdot2(u2h2(b2), wb, __builtin_amdgcn_fdot2(u2h2(t2), wt, 0.f, false), false);
      float v3 = __builtin_amdgcn_fdot2(u2h2(b3), wb, __builtin_amdgcn_fdot2(u2h2(t3), wt, 0.f, false), false);
      ac[p][0] = fmaf(v0, wk4.x, ac[p][0]);
      ac[p][1] = fmaf(v1, wk4.y, ac[p][1]);
      ac[p][2] = fmaf(v2, wk4.z, ac[p][2]);
      ac[p][3] = fmaf(v3, wk4.w, ac[p][3]);
    }
  }
  float4 bd = *(const float4*)(b_dw + c0);
#pragma unroll
  for (int p = 0; p < 4; p++) {
    int n = n0 + pg + p * 8;
    ushort4 ov;
    ov.x = f2h_bits(ac[p][0] + bd.x);
    ov.y = f2h_bits(ac[p][1] + bd.y);
    ov.z = f2h_bits(ac[p][2] + bd.z);
    ov.w = f2h_bits(ac[p][3] + bd.w);
    *(ushort4*)(out1h + (size_t)n * CC + c0) = ov;
  }
}

// ---------------------------------------------------------------------------
// P4: pointwise GEMM, f16 MFMA. Block = 4 waves; block tile 256o x 64n.
// ---------------------------------------------------------------------------
__global__ __launch_bounds__(256) void k_pw_mfma(const _Float16* __restrict__ Apw,
                                                 const _Float16* __restrict__ out1h,
                                                 const float* __restrict__ bpw,
                                                 float* __restrict__ out) {
  int bid = blockIdx.x;
  int n0 = ((bid & 7) * 128 + (bid >> 3)) * 64;
  int tid = threadIdx.x;
  int wv = tid >> 6, lane = tid & 63;
  int n16 = lane & 15, quad = lane >> 4;
  int obase = wv * 64;

  floatx4 acc[4][4] = {};   // [mf][nf]
#pragma unroll
  for (int cs = 0; cs < 4; cs++) {
    half8 af[4], bf[4];
#pragma unroll
    for (int mf = 0; mf < 4; mf++) {
      const _Float16* pa = Apw + ((size_t)(cs * 4 + quad) * 256 + obase + mf * 16 + n16) * 8;
      af[mf] = *(const half8*)pa;
    }
#pragma unroll
    for (int nf = 0; nf < 4; nf++) {
      const _Float16* pb = out1h + (size_t)(n0 + nf * 16 + n16) * CC + cs * 32 + quad * 8;
      bf[nf] = *(const half8*)pb;
    }
#pragma unroll
    for (int mf = 0; mf < 4; mf++)
#pragma unroll
      for (int nf = 0; nf < 4; nf++)
        acc[mf][nf] = __builtin_amdgcn_mfma_f32_16x16x32_f16(af[mf], bf[nf], acc[mf][nf], 0, 0, 0);
  }
  int b = n0 >> 14;
#pragma unroll
  for (int mf = 0; mf < 4; mf++) {
#pragma unroll
    for (int reg = 0; reg < 4; reg++) {
      int o = obase + mf * 16 + quad * 4 + reg;
      float bo = bpw[o];
#pragma unroll
      for (int nf = 0; nf < 4; nf++) {
        int n = n0 + nf * 16 + n16;
        int hw = n & 16383;
        out[((size_t)(b * OO + o) << 14) + hw] = acc[mf][nf][reg] + bo;
      }
    }
  }
}

// ---------------------------------------------------------------------------
extern "C" void kernel_launch(void* const* d_in, const int* in_sizes, int n_in,
                              void* d_out, int out_size, void* d_ws, size_t ws_size,
                              hipStream_t stream) {
  const float* x     = (const float*)d_in[0];
  const float* w_off = (const float*)d_in[1];
  const float* b_off = (const float*)d_in[2];
  const float* w_dw  = (const float*)d_in[3];
  const float* b_dw  = (const float*)d_in[4];
  const float* w_pw  = (const float*)d_in[5];
  const float* b_pw  = (const float*)d_in[6];
  float* out = (float*)d_out;
  float* ws  = (float*)d_ws;

  // d_out scratch (dead before k_pw_mfma writes):
  //   xh : f16 NHWC, 8388608 elems = 16.78 MB at byte offset 0
  _Float16* xh = (_Float16*)out;

  // ws layout (float offsets):
  //   out1h : f16, 8388608 elems = 4194304 floats -> [0, 4194304)
  //   Ah    : f16 36864  -> at 4194304
  //   Apw   : f16 32768
  _Float16* out1h = (_Float16*)ws;
  _Float16* Ah = (_Float16*)(ws + 4194304);
  _Float16* Apw = Ah + 36864;

  k_transpose<<<dim3(4, 128, 5), 256, 0, stream>>>(x, w_off, w_pw,
                                                   (unsigned int*)xh, Ah, Apw);
  k_fused<<<2048, 256, 0, stream>>>(xh, Ah, b_off, w_dw, b_dw,
                                    (unsigned short*)out1h);
  k_pw_mfma<<<1024, 256, 0, stream>>>(Apw, out1h, b_pw, out);
}

// Round 3
// 161.314 us; speedup vs baseline: 1.2157x; 1.1114x over previous
//
#include <hip/hip_runtime.h>
#include <hip/hip_bf16.h>
#include <math.h>

#define BB 4
#define CC 128
#define HH 128
#define WW 128
#define OO 256
#define HWP 16384   // H*W

typedef __attribute__((ext_vector_type(8))) _Float16 half8;   // f16x8 MFMA frag
typedef __attribute__((ext_vector_type(2))) _Float16 half2t;  // v_dot2 operand
typedef __attribute__((ext_vector_type(4))) float floatx4;    // MFMA C/D frag

__device__ inline half2t u2h2(unsigned int u) {
  union { unsigned int i; half2t h; } z; z.i = u; return z.h;
}
__device__ inline unsigned short f2h_bits(float f) {
  union { _Float16 h; unsigned short s; } z; z.h = (_Float16)f; return z.s;
}

// bilinear blend for 2 channels packed in one dword per corner
__device__ inline void blend2(unsigned int a00w, unsigned int a01w,
                              unsigned int a10w, unsigned int a11w,
                              half2t wt, half2t wb, float wk0, float wk1,
                              float& acc0, float& acc1) {
  unsigned int tl = __builtin_amdgcn_perm(a01w, a00w, 0x05040100u);
  unsigned int th = __builtin_amdgcn_perm(a01w, a00w, 0x07060302u);
  unsigned int bl = __builtin_amdgcn_perm(a11w, a10w, 0x05040100u);
  unsigned int bh = __builtin_amdgcn_perm(a11w, a10w, 0x07060302u);
  float v0 = __builtin_amdgcn_fdot2(u2h2(bl), wb, __builtin_amdgcn_fdot2(u2h2(tl), wt, 0.f, false), false);
  float v1 = __builtin_amdgcn_fdot2(u2h2(bh), wb, __builtin_amdgcn_fdot2(u2h2(th), wt, 0.f, false), false);
  acc0 = fmaf(v0, wk0, acc0);
  acc1 = fmaf(v1, wk1, acc1);
}

// ---------------------------------------------------------------------------
// P1: fused NCHW->NHWC f16 transpose (z<4) + weight prep (z==4).
// ---------------------------------------------------------------------------
__global__ __launch_bounds__(256) void k_transpose(const float* __restrict__ x,
                                                   const float* __restrict__ w_off,
                                                   const float* __restrict__ w_pw,
                                                   unsigned int* __restrict__ xh32,
                                                   _Float16* __restrict__ Ah,
                                                   _Float16* __restrict__ Apw) {
  int tid = threadIdx.x;
  if (blockIdx.z == 4) {
    int e = (blockIdx.x * 128 + blockIdx.y) * 256 + tid;
    if (e < 144 * 32 * 8) {   // offconv A: [kblk=144][o=32][8], k = t*128+c
      int kblk = e >> 8;
      int o = (e >> 3) & 31;
      int j = e & 7;
      int k = kblk * 8 + j;
      int t = k >> 7, c = k & 127;
      float w = (o < 27) ? w_off[(o * CC + c) * 9 + t] : 0.0f;
      Ah[e] = (_Float16)w;
    }
    int e2 = e - 144 * 32 * 8;
    if (e2 >= 0 && e2 < 16 * 256 * 8) {   // pw A: [cblk=16][o=256][8]
      int cblk = e2 >> 11;
      int o = (e2 >> 3) & 255;
      int j = e2 & 7;
      Apw[e2] = (_Float16)w_pw[o * CC + cblk * 8 + j];
    }
    return;
  }
  __shared__ float tile[64][65];   // [c'][w']
  int wt = blockIdx.x & 1;
  int ct = blockIdx.x >> 1;
  int h = blockIdx.y, b = blockIdx.z;
  int tw = tid & 63;
  int tc = tid >> 6;
#pragma unroll
  for (int i = 0; i < 16; i++) {
    int c = ct * 64 + i * 4 + tc;
    tile[i * 4 + tc][tw] = x[((b * CC + c) * HH + h) * WW + wt * 64 + tw];
  }
  __syncthreads();
  int cp = tid & 31;        // channel pair within 64-ch tile
  int wq = tid >> 5;        // 8 w-groups
#pragma unroll
  for (int i = 0; i < 8; i++) {
    int wp = i * 8 + wq;    // w' in [0,64)
    int w = wt * 64 + wp;
    unsigned short h0 = f2h_bits(tile[cp * 2][wp]);
    unsigned short h1 = f2h_bits(tile[cp * 2 + 1][wp]);
    int idx2 = (((b * HH + h) * WW + w) * CC + ct * 64 + cp * 2) >> 1;
    xh32[idx2] = (unsigned int)h0 | ((unsigned int)h1 << 16);
  }
}

// ---------------------------------------------------------------------------
// MEGA-FUSED: offconv MFMA + deformable sampling + depthwise + pointwise GEMM.
// Block = 64 consecutive pixels of one row. Grid 1024, XCD-swizzled.
//  Phase A: wave wv owns 16 px, runs FULL K=36 offconv (no K-split/reduce)
//           -> om_s[64][28] (+bias).
//  Prologue: 576 (px,tap) items -> bilinear tables + dw weights in LDS.
//  Phase B: thread owns 8ch x 4px; 16B dwordx4 gathers (half the instr count
//           of r2 per output); dot2 blend + depthwise; result (f16+bias) ->
//           val[64][128] in LDS, XOR-swizzled (unit ^= row&7, 2-way free).
//  Phase C: pointwise 256o x 64n x 128c MFMA from LDS val + L2-hot Apw;
//           writes final f32 NCHW output. out1h round-trip eliminated.
// ---------------------------------------------------------------------------
__global__ __launch_bounds__(256, 2) void k_fused(
    const _Float16* __restrict__ xh, const _Float16* __restrict__ Ah,
    const _Float16* __restrict__ Apw, const float* __restrict__ b_off,
    const float* __restrict__ w_dw, const float* __restrict__ b_dw,
    const float* __restrict__ bpw, float* __restrict__ out) {
  __shared__ float om_s[64][28];
  __shared__ int s_base[64][9];
  __shared__ int s_dxs[64][9];
  __shared__ int s_dys[64][9];
  __shared__ unsigned int s_wp[64][9][2];
  __shared__ float s_wk[9][128];
  __shared__ __align__(16) _Float16 val[64][128];   // XOR-swizzled f16 dw output

  int tid = threadIdx.x;
  int bid = blockIdx.x;
  int n0 = ((bid & 7) * 128 + (bid >> 3)) * 64;   // XCD-contiguous bands
  int b = n0 >> 14;
  int h0 = (n0 >> 7) & 127;
  int wbase = n0 & 127;   // 0 or 64

  int wv = tid >> 6, lane = tid & 63;
  int n16 = lane & 15, quad = lane >> 4;

  // ---- Phase A: offconv, wave wv owns pixels [wv*16, wv*16+16), full K
  {
    int pxb = wv * 16;
    floatx4 acc0 = {}, acc1 = {};
    half8 zz = {};
#pragma unroll
    for (int t = 0; t < 9; t++) {
      int dy = t / 3 - 1, dx = t % 3 - 1;
      int hs = h0 + dy;
      bool hok = ((unsigned)hs < HH);
      int hsc = min(max(hs, 0), HH - 1);
      int wA = wbase + pxb + n16 + dx;
      bool okA = hok && ((unsigned)wA < WW);
      int wAc = min(max(wA, 0), WW - 1);
      size_t rowoff = (size_t)((b * HH + hsc) * WW + wAc) * CC + quad * 8;
#pragma unroll
      for (int cs = 0; cs < 4; cs++) {
        half8 bh = *(const half8*)(xh + rowoff + cs * 32);
        bh = okA ? bh : zz;
        int kblk = t * 16 + cs * 4 + quad;
        const _Float16* pa = Ah + (size_t)kblk * 256 + n16 * 8;
        half8 a0 = *(const half8*)pa;
        half8 a1 = *(const half8*)(pa + 128);
        acc0 = __builtin_amdgcn_mfma_f32_16x16x32_f16(a0, bh, acc0, 0, 0, 0);
        acc1 = __builtin_amdgcn_mfma_f32_16x16x32_f16(a1, bh, acc1, 0, 0, 0);
      }
    }
    int px = pxb + n16;
#pragma unroll
    for (int reg = 0; reg < 4; reg++) {
      int o0 = quad * 4 + reg;
      om_s[px][o0] = acc0[reg] + b_off[o0];
      int o1 = 16 + quad * 4 + reg;
      if (o1 < 27) om_s[px][o1] = acc1[reg] + b_off[o1];
    }
  }
  __syncthreads();

  // ---- Prologue: dw weights + per-(px,tap) bilinear tables
  for (int i = tid; i < 1152; i += 256) s_wk[i % 9][i / 9] = w_dw[i];
  for (int it = tid; it < 576; it += 256) {
    int px = it / 9, k = it - px * 9;
    int w = wbase + px;
    float dyv = om_s[px][2 * k];
    float dxv = om_s[px][2 * k + 1];
    float mv = om_s[px][18 + k];
    mv = 1.0f / (1.0f + __expf(-mv));
    float py = (float)(h0 + k / 3 - 1) + dyv;
    float pxf = (float)(w + k % 3 - 1) + dxv;
    float y0f = floorf(py), x0f = floorf(pxf);
    float wy = py - y0f, wx = pxf - x0f;
    int y0 = (int)y0f, x0 = (int)x0f;
    int y1 = y0 + 1, x1 = x0 + 1;
    float v00 = (y0 >= 0 && y0 < HH && x0 >= 0 && x0 < WW) ? 1.f : 0.f;
    float v01 = (y0 >= 0 && y0 < HH && x1 >= 0 && x1 < WW) ? 1.f : 0.f;
    float v10 = (y1 >= 0 && y1 < HH && x0 >= 0 && x0 < WW) ? 1.f : 0.f;
    float v11 = (y1 >= 0 && y1 < HH && x1 >= 0 && x1 < WW) ? 1.f : 0.f;
    int y0c = min(max(y0, 0), HH - 1), y1c = min(max(y1, 0), HH - 1);
    int x0c = min(max(x0, 0), WW - 1), x1c = min(max(x1, 0), WW - 1);
    s_base[px][k] = ((b * HH + y0c) * WW + x0c) * CC;
    s_dxs[px][k] = (x1c - x0c) * CC;
    s_dys[px][k] = (y1c - y0c) * WW * CC;
    float w00 = (1.f - wy) * (1.f - wx) * mv * v00;
    float w01 = (1.f - wy) * wx * mv * v01;
    float w10 = wy * (1.f - wx) * mv * v10;
    float w11 = wy * wx * mv * v11;
    s_wp[px][k][0] = (unsigned int)f2h_bits(w00) | ((unsigned int)f2h_bits(w01) << 16);
    s_wp[px][k][1] = (unsigned int)f2h_bits(w10) | ((unsigned int)f2h_bits(w11) << 16);
  }
  __syncthreads();

  // ---- Phase B: sampling + depthwise; thread = 8 channels x 4 pixels
  {
    int cl = lane & 15;          // channel group (8 ch)
    int pgl = lane >> 4;         // pixel slot within wave
    int slot = wv * 4 + pgl;     // 0..15
    int c0 = cl * 8;
    const unsigned short* xs = (const unsigned short*)xh;

    float ac[4][8];
#pragma unroll
    for (int p = 0; p < 4; p++)
#pragma unroll
      for (int j = 0; j < 8; j++) ac[p][j] = 0.f;

#pragma unroll
    for (int k = 0; k < 9; k++) {
      float4 wka = *(const float4*)&s_wk[k][c0];
      float4 wkb = *(const float4*)&s_wk[k][c0 + 4];
#pragma unroll
      for (int p = 0; p < 4; p++) {
        int pix = slot + p * 16;
        int base = s_base[pix][k] + c0;
        int dxs = s_dxs[pix][k], dys = s_dys[pix][k];
        uint4 a00 = *(const uint4*)(xs + base);
        uint4 a01 = *(const uint4*)(xs + base + dxs);
        uint4 a10 = *(const uint4*)(xs + base + dys);
        uint4 a11 = *(const uint4*)(xs + base + dys + dxs);
        half2t wt = u2h2(s_wp[pix][k][0]);
        half2t wb = u2h2(s_wp[pix][k][1]);
        blend2(a00.x, a01.x, a10.x, a11.x, wt, wb, wka.x, wka.y, ac[p][0], ac[p][1]);
        blend2(a00.y, a01.y, a10.y, a11.y, wt, wb, wka.z, wka.w, ac[p][2], ac[p][3]);
        blend2(a00.z, a01.z, a10.z, a11.z, wt, wb, wkb.x, wkb.y, ac[p][4], ac[p][5]);
        blend2(a00.w, a01.w, a10.w, a11.w, wt, wb, wkb.z, wkb.w, ac[p][6], ac[p][7]);
      }
    }
    float4 bd0 = *(const float4*)(b_dw + c0);
    float4 bd1 = *(const float4*)(b_dw + c0 + 4);
#pragma unroll
    for (int p = 0; p < 4; p++) {
      int pix = slot + p * 16;
      uint4 pk;
      pk.x = (unsigned int)f2h_bits(ac[p][0] + bd0.x) | ((unsigned int)f2h_bits(ac[p][1] + bd0.y) << 16);
      pk.y = (unsigned int)f2h_bits(ac[p][2] + bd0.z) | ((unsigned int)f2h_bits(ac[p][3] + bd0.w) << 16);
      pk.z = (unsigned int)f2h_bits(ac[p][4] + bd1.x) | ((unsigned int)f2h_bits(ac[p][5] + bd1.y) << 16);
      pk.w = (unsigned int)f2h_bits(ac[p][6] + bd1.z) | ((unsigned int)f2h_bits(ac[p][7] + bd1.w) << 16);
      int su = cl ^ (pix & 7);           // XOR swizzle, 16B units
      *(uint4*)&val[pix][su * 8] = pk;
    }
  }
  __syncthreads();

  // ---- Phase C: pointwise GEMM 256o x 64n x 128c; wave wv -> o [wv*64, +64)
  {
    int obase = wv * 64;
    floatx4 acc[4][4] = {};   // [mf][nf]
#pragma unroll
    for (int cs = 0; cs < 4; cs++) {
      half8 af[4], bf[4];
#pragma unroll
      for (int mf = 0; mf < 4; mf++) {
        const _Float16* pa = Apw + ((size_t)(cs * 4 + quad) * 256 + obase + mf * 16 + n16) * 8;
        af[mf] = *(const half8*)pa;
      }
#pragma unroll
      for (int nf = 0; nf < 4; nf++) {
        int row = nf * 16 + n16;
        int su = (cs * 4 + quad) ^ (row & 7);
        bf[nf] = *(const half8*)&val[row][su * 8];
      }
#pragma unroll
      for (int mf = 0; mf < 4; mf++)
#pragma unroll
        for (int nf = 0; nf < 4; nf++)
          acc[mf][nf] = __builtin_amdgcn_mfma_f32_16x16x32_f16(af[mf], bf[nf], acc[mf][nf], 0, 0, 0);
    }
#pragma unroll
    for (int mf = 0; mf < 4; mf++) {
#pragma unroll
      for (int reg = 0; reg < 4; reg++) {
        int o = obase + mf * 16 + quad * 4 + reg;
        float bo = bpw[o];
#pragma unroll
        for (int nf = 0; nf < 4; nf++) {
          int n = n0 + nf * 16 + n16;
          int hw = n & 16383;
          out[((size_t)(b * OO + o) << 14) + hw] = acc[mf][nf][reg] + bo;
        }
      }
    }
  }
}

// ---------------------------------------------------------------------------
extern "C" void kernel_launch(void* const* d_in, const int* in_sizes, int n_in,
                              void* d_out, int out_size, void* d_ws, size_t ws_size,
                              hipStream_t stream) {
  const float* x     = (const float*)d_in[0];
  const float* w_off = (const float*)d_in[1];
  const float* b_off = (const float*)d_in[2];
  const float* w_dw  = (const float*)d_in[3];
  const float* b_dw  = (const float*)d_in[4];
  const float* w_pw  = (const float*)d_in[5];
  const float* b_pw  = (const float*)d_in[6];
  float* out = (float*)d_out;
  float* ws  = (float*)d_ws;

  // ws layout (byte offsets):
  //   xh  : f16 NHWC, 8388608 elems = 16,777,216 B  at 0
  //   Ah  : f16 36864 elems                          at 16,777,216
  //   Apw : f16 65536 elems                          after Ah
  // (xh must NOT alias d_out anymore: k_fused writes out while reading xh)
  _Float16* xh  = (_Float16*)ws;
  _Float16* Ah  = (_Float16*)((char*)ws + 16777216);
  _Float16* Apw = Ah + 36864;

  k_transpose<<<dim3(4, 128, 5), 256, 0, stream>>>(x, w_off, w_pw,
                                                   (unsigned int*)xh, Ah, Apw);
  k_fused<<<1024, 256, 0, stream>>>(xh, Ah, Apw, b_off, w_dw, b_dw, b_pw, out);
}